// Round 1
// baseline (14.436 us; speedup 1.0000x reference)
//
#include <hip/hip_runtime.h>
#include <math.h>

// Problem constants (from the reference)
#define NBATCH 16384
#define NJOINT 32
#define MIN_TH2 0.25f   // 0.5^2
#define MAX_TH2 4.0f    // 2.0^2

#define BATCHES_PER_BLOCK 8
#define BLOCK 256                                  // 8 batches * 32 joints
#define NBLK (NBATCH / BATCHES_PER_BLOCK)          // 2048
#define FLOATS_PER_BLOCK (BATCHES_PER_BLOCK * NJOINT * 3)  // 768

__global__ void __launch_bounds__(BLOCK) sep_loss_part1(
        const float* __restrict__ kps, float* __restrict__ partial) {
    __shared__ float lds[FLOATS_PER_BLOCK];   // 3 KB
    __shared__ float wsum[BLOCK / 64];        // per-wave partial sums

    const int tid = threadIdx.x;
    const long long base = (long long)blockIdx.x * FLOATS_PER_BLOCK;

    // Coalesced stage: 768 contiguous floats, 3 per thread.
    #pragma unroll
    for (int k = 0; k < FLOATS_PER_BLOCK / BLOCK; ++k)
        lds[tid + k * BLOCK] = kps[base + tid + k * BLOCK];
    __syncthreads();

    const int b_local = tid >> 5;   // 0..7  : which batch item in this block
    const int i       = tid & 31;   // 0..31 : which joint this thread owns
    const float* jb = &lds[b_local * (NJOINT * 3)];

    const float xi = jb[i * 3 + 0];
    const float yi = jb[i * 3 + 1];
    const float zi = jb[i * 3 + 2];

    float acc = 0.0f;
    #pragma unroll
    for (int j = 0; j < NJOINT; ++j) {
        const float dx = xi - jb[j * 3 + 0];
        const float dy = yi - jb[j * 3 + 1];
        const float dz = zi - jb[j * 3 + 2];
        const float d2 = dx * dx + dy * dy + dz * dz;
        float pen = fmaxf(0.0f, MIN_TH2 - d2) + fmaxf(0.0f, d2 - MAX_TH2);
        if (j == i) pen = 0.0f;     // exclude diagonal (d2=0 would add MIN_TH2)
        acc += pen;
    }

    // Wave (64-lane) shuffle reduce.
    #pragma unroll
    for (int off = 32; off > 0; off >>= 1)
        acc += __shfl_down(acc, off, 64);

    const int wave = tid >> 6;       // 0..3
    if ((tid & 63) == 0) wsum[wave] = acc;
    __syncthreads();

    if (tid == 0)
        partial[blockIdx.x] = wsum[0] + wsum[1] + wsum[2] + wsum[3];
}

__global__ void __launch_bounds__(BLOCK) sep_loss_part2(
        const float* __restrict__ partial, float* __restrict__ out) {
    __shared__ float wsum[BLOCK / 64];

    float acc = 0.0f;
    for (int k = threadIdx.x; k < NBLK; k += BLOCK)
        acc += partial[k];

    #pragma unroll
    for (int off = 32; off > 0; off >>= 1)
        acc += __shfl_down(acc, off, 64);

    const int wave = threadIdx.x >> 6;
    if ((threadIdx.x & 63) == 0) wsum[wave] = acc;
    __syncthreads();

    if (threadIdx.x == 0) {
        const float total = wsum[0] + wsum[1] + wsum[2] + wsum[3];
        const float mean = total / (float)NBATCH;
        out[0] = powf(mean, 0.4f);
    }
}

extern "C" void kernel_launch(void* const* d_in, const int* in_sizes, int n_in,
                              void* d_out, int out_size, void* d_ws, size_t ws_size,
                              hipStream_t stream) {
    const float* kps = (const float*)d_in[0];
    float* out = (float*)d_out;
    float* partial = (float*)d_ws;   // NBLK floats = 8 KB

    sep_loss_part1<<<NBLK, BLOCK, 0, stream>>>(kps, partial);
    sep_loss_part2<<<1, BLOCK, 0, stream>>>(partial, out);
}